// Round 10
// baseline (86.908 us; speedup 1.0000x reference)
//
#include <hip/hip_runtime.h>
#include <cstdint>
#include <cstddef>

#define BB 32
#define AA 8400
#define NBB 32
#define CC 80
#define TOPKN 10

// ===========================================================================
// K1 (v2): per (b,j), ONE WAVE (64 threads). Enumerate only anchors inside
// the gt box via the analytic 3-level grid (bit-exact recompute of
// (arange+0.5)*s in f32), exact d>1e-8 re-test. Per-thread top-10 insertion
// (~6 candidates/thread), then 6-round LDS merge with [64][11] padding
// (row stride 88B -> 2-way bank aliasing = free) and cheap 1-wave barriers.
// key = align_bits<<32 | (8400-a): descending u64 == descending align,
// tie -> smaller anchor index (lax.top_k semantics).
// ===========================================================================
__global__ __launch_bounds__(64) void gt_topk_kernel(
    const float* __restrict__ pred_scores, const float* __restrict__ pred_boxes,
    const int* __restrict__ gt_labels, const float* __restrict__ gt_boxes,
    const int* __restrict__ gt_mask,
    int* __restrict__ tk, int* __restrict__ posA, int* __restrict__ posI) {
  const int j = blockIdx.x, b = blockIdx.y, t = threadIdx.x;  // t in [0,64)
  const int g = b * NBB + j;
  if (t == 0) { posA[g] = 0; posI[g] = 0; }  // owner-zeroed; K2 maxes later

  const float gx0 = gt_boxes[g * 4 + 0], gy0 = gt_boxes[g * 4 + 1];
  const float gx1 = gt_boxes[g * 4 + 2], gy1 = gt_boxes[g * 4 + 3];
  const int cls = gt_labels[g];
  const bool valid = (gt_mask[g] != 0);
  const float ga1 = (gx1 - gx0) * (gy1 - gy0);

  unsigned long long tkkey[TOPKN];
#pragma unroll
  for (int k = 0; k < TOPKN; k++) tkkey[k] = 0ull;

  if (valid) {
    const int strides[3] = {8, 16, 32};
    const int grids[3] = {80, 40, 20};
    const int offs[3] = {0, 6400, 8000};
    for (int lvl = 0; lvl < 3; lvl++) {
      const float s = (float)strides[lvl];
      const int n = grids[lvl], off = offs[lvl];
      int lx = max(0, (int)floorf(gx0 / s - 0.5f) - 1);
      int hx = min(n - 1, (int)ceilf(gx1 / s - 0.5f) + 1);
      int ly = max(0, (int)floorf(gy0 / s - 0.5f) - 1);
      int hy = min(n - 1, (int)ceilf(gy1 / s - 0.5f) + 1);
      if (hx < lx || hy < ly) continue;
      const int w = hx - lx + 1;
      const int m = w * (hy - ly + 1);
      for (int i = t; i < m; i += 64) {
        const int ix = lx + i % w;
        const int iy = ly + i / w;
        const float apx = ((float)ix + 0.5f) * s;
        const float apy = ((float)iy + 0.5f) * s;
        const float d = fminf(fminf(apx - gx0, apy - gy0),
                              fminf(gx1 - apx, gy1 - apy));
        if (!(d > 1e-8f)) continue;
        const int a = off + iy * n + ix;
        const float* pb = pred_boxes + ((size_t)b * AA + a) * 4;
        const float p0 = pb[0], p1 = pb[1], p2 = pb[2], p3 = pb[3];
        const float iw = fmaxf(fminf(gx1, p2) - fmaxf(gx0, p0), 0.0f);
        const float ih = fmaxf(fminf(gy1, p3) - fmaxf(gy0, p1), 0.0f);
        const float inter = iw * ih;
        const float a2 = (p2 - p0) * (p3 - p1);
        const float iou = fmaxf(inter / (ga1 + a2 - inter + 1e-10f), 0.0f);
        const float sc = pred_scores[((size_t)b * AA + a) * CC + cls];
        const float i2 = iou * iou;
        const float align_v = sc * i2 * i2 * i2;
        const unsigned long long key =
            ((unsigned long long)__float_as_uint(align_v) << 32) |
            (unsigned int)(AA - a);
        if (key > tkkey[TOPKN - 1]) {
          tkkey[TOPKN - 1] = key;
#pragma unroll
          for (int k = TOPKN - 1; k > 0; k--) {
            if (tkkey[k] > tkkey[k - 1]) {
              unsigned long long tmp = tkkey[k];
              tkkey[k] = tkkey[k - 1];
              tkkey[k - 1] = tmp;
            }
          }
        }
      }
    }
  }

  // 1-wave LDS merge tree; +1 u64 pad per row -> 2-way bank aliasing (free)
  __shared__ unsigned long long s_key[64][TOPKN + 1];
#pragma unroll
  for (int k = 0; k < TOPKN; k++) s_key[t][k] = tkkey[k];
  __syncthreads();

  for (int stride = 32; stride >= 1; stride >>= 1) {
    if (t < stride) {
      unsigned long long mk[TOPKN];
      int p = 0, q = 0;
#pragma unroll
      for (int k = 0; k < TOPKN; k++) {
        const unsigned long long k1 = s_key[t][p], k2 = s_key[t + stride][q];
        if (k1 >= k2) { mk[k] = k1; p++; } else { mk[k] = k2; q++; }
      }
#pragma unroll
      for (int k = 0; k < TOPKN; k++) s_key[t][k] = mk[k];
    }
    __syncthreads();
  }

  if (t < TOPKN) {
    const unsigned long long key = s_key[0][t];
    tk[g * TOPKN + t] = (key != 0ull) ? (AA - (int)(key & 0xffffffffu)) : -1;
  }
}

// ===========================================================================
// K2: per anchor (unchanged from R9). 32-gt loop: inside test + iou;
// membership = scan of the 10 stored indices; cnt==1 -> member j, cnt>1 ->
// first-max argmax_j iou. One score gather per assigned anchor. atomicMax
// pos_align/pos_iou (nonneg float as int bits).
// ===========================================================================
__global__ __launch_bounds__(256) void assign_kernel(
    const float* __restrict__ pred_scores, const float* __restrict__ pred_boxes,
    const float* __restrict__ anchor_points, const int* __restrict__ gt_labels,
    const float* __restrict__ gt_boxes, const int* __restrict__ gt_mask,
    const int* __restrict__ tk,
    int* __restrict__ assign_ws, float* __restrict__ align_ws,
    int* __restrict__ posA, int* __restrict__ posI) {
  const int b = blockIdx.y, t = threadIdx.x;
  const int a = blockIdx.x * 256 + t;

  __shared__ float sbox[NBB][4];
  __shared__ int scls[NBB];
  __shared__ int svalid[NBB];
  __shared__ int stk[NBB][TOPKN];

  if (t < NBB) {
    const int g = b * NBB + t;
    sbox[t][0] = gt_boxes[g * 4 + 0];
    sbox[t][1] = gt_boxes[g * 4 + 1];
    sbox[t][2] = gt_boxes[g * 4 + 2];
    sbox[t][3] = gt_boxes[g * 4 + 3];
    scls[t] = gt_labels[g];
    svalid[t] = (gt_mask[g] != 0) ? 1 : 0;
  }
  for (int i = t; i < NBB * TOPKN; i += 256)
    stk[i / TOPKN][i % TOPKN] = tk[b * NBB * TOPKN + i];
  __syncthreads();

  if (a >= AA) return;

  const float apx = anchor_points[a * 2 + 0];
  const float apy = anchor_points[a * 2 + 1];
  const float* pb = pred_boxes + ((size_t)b * AA + a) * 4;
  const float p0 = pb[0], p1 = pb[1], p2 = pb[2], p3 = pb[3];
  const float a2 = (p2 - p0) * (p3 - p1);

  int cnt = 0, memj = 0;
  float mem_iou = 0.0f;
  float best_iou = -1.0f;
  int best_j = 0;

  for (int j = 0; j < NBB; j++) {
    const float gx0 = sbox[j][0], gy0 = sbox[j][1];
    const float gx1 = sbox[j][2], gy1 = sbox[j][3];
    const float d = fminf(fminf(apx - gx0, apy - gy0),
                          fminf(gx1 - apx, gy1 - apy));
    const bool vin = svalid[j] && (d > 1e-8f);
    float iou = 0.0f;
    if (vin) {
      const float iw = fmaxf(fminf(gx1, p2) - fmaxf(gx0, p0), 0.0f);
      const float ih = fmaxf(fminf(gy1, p3) - fmaxf(gy0, p1), 0.0f);
      const float inter = iw * ih;
      const float a1 = (gx1 - gx0) * (gy1 - gy0);
      iou = fmaxf(inter / (a1 + a2 - inter + 1e-10f), 0.0f);
    }
    if (iou > best_iou) { best_iou = iou; best_j = j; }  // first-max
    if (vin) {
      bool member = false;
#pragma unroll
      for (int k = 0; k < TOPKN; k++) member = member || (stk[j][k] == a);
      if (member) { cnt++; memj = j; mem_iou = iou; }
    }
  }

  int assign = -1;
  float align_v = 0.0f;
  if (cnt > 0) {
    const int jj = (cnt == 1) ? memj : best_j;
    const float iou_f = (cnt == 1) ? mem_iou : best_iou;
    const float sc = pred_scores[((size_t)b * AA + a) * CC + scls[jj]];
    const float i2 = iou_f * iou_f;
    align_v = sc * i2 * i2 * i2;
    assign = jj;
    atomicMax(&posA[b * NBB + jj], __float_as_int(align_v));
    atomicMax(&posI[b * NBB + jj], __float_as_int(iou_f));
  }
  assign_ws[b * AA + a] = assign;
  align_ws[b * AA + a] = align_v;
}

// ===========================================================================
// K3: write the whole output (unchanged from R9). One thread per float4
// chunk of the scores tensor (20/anchor); chunk-0 thread also writes
// label/box/fg.
// ===========================================================================
__global__ __launch_bounds__(256) void write_out_kernel(
    const int* __restrict__ gt_labels, const float* __restrict__ gt_boxes,
    const int* __restrict__ assign_in, const float* __restrict__ align_in,
    const int* __restrict__ posA, const int* __restrict__ posI,
    float* __restrict__ out) {
  const int idx = blockIdx.x * 256 + threadIdx.x;  // [0, BB*AA*20)
  const int aidx = idx / 20;
  const int c = idx - aidx * 20;
  const int b = aidx / AA;

  const int assign = assign_in[aidx];
  const int j0 = (assign >= 0) ? assign : 0;
  const int g = b * NBB + j0;
  int label = gt_labels[g];
  label = min(max(label, 0), 80);

  float* out_scores = out + (size_t)BB * AA * 5;
  float4 vv = make_float4(0.f, 0.f, 0.f, 0.f);
  if (assign >= 0 && c == (label >> 2)) {
    const float pa = __int_as_float(posA[b * NBB + assign]);
    const float pi = __int_as_float(posI[b * NBB + assign]);
    const float norm = align_in[aidx] * pi / (pa + 1e-8f);
    ((float*)&vv)[label & 3] = norm;
  }
  reinterpret_cast<float4*>(out_scores)[(size_t)aidx * 20 + c] = vv;

  if (c == 0) {
    out[aidx] = (float)label;
    float* out_boxes = out + (size_t)BB * AA;
    out_boxes[(size_t)aidx * 4 + 0] = gt_boxes[g * 4 + 0];
    out_boxes[(size_t)aidx * 4 + 1] = gt_boxes[g * 4 + 1];
    out_boxes[(size_t)aidx * 4 + 2] = gt_boxes[g * 4 + 2];
    out_boxes[(size_t)aidx * 4 + 3] = gt_boxes[g * 4 + 3];
    out[(size_t)BB * AA * 85 + aidx] = (assign >= 0) ? 1.0f : 0.0f;
  }
}

// ===========================================================================
extern "C" void kernel_launch(void* const* d_in, const int* in_sizes, int n_in,
                              void* d_out, int out_size, void* d_ws, size_t ws_size,
                              hipStream_t stream) {
  const float* pred_scores = (const float*)d_in[0];
  const float* pred_boxes = (const float*)d_in[1];
  const float* anchor_points = (const float*)d_in[2];
  const int* gt_labels = (const int*)d_in[3];
  const float* gt_boxes = (const float*)d_in[4];
  const int* gt_mask = (const int*)d_in[5];
  float* out = (float*)d_out;
  char* ws = (char*)d_ws;

  // workspace layout (bytes)
  const size_t sz_acc = (size_t)BB * AA * 4;               // 1.075 MB
  const size_t off_tk = 0;                                 // 1024*10*4 = 40KB
  const size_t off_posA = off_tk + (size_t)BB * NBB * TOPKN * 4;
  const size_t off_posI = off_posA + 4096;
  const size_t off_assign = off_posI + 4096;
  const size_t off_align = off_assign + sz_acc;

  int* tk = (int*)(ws + off_tk);
  int* posA = (int*)(ws + off_posA);
  int* posI = (int*)(ws + off_posI);
  int* assign_ws = (int*)(ws + off_assign);
  float* align_ws = (float*)(ws + off_align);

  dim3 g1(NBB, BB);
  gt_topk_kernel<<<g1, 64, 0, stream>>>(pred_scores, pred_boxes, gt_labels,
                                        gt_boxes, gt_mask, tk, posA, posI);

  dim3 g2((AA + 255) / 256, BB);
  assign_kernel<<<g2, 256, 0, stream>>>(pred_scores, pred_boxes, anchor_points,
                                        gt_labels, gt_boxes, gt_mask, tk,
                                        assign_ws, align_ws, posA, posI);

  const int nchunks = BB * AA * 20;
  write_out_kernel<<<(nchunks + 255) / 256, 256, 0, stream>>>(
      gt_labels, gt_boxes, assign_ws, align_ws, posA, posI, out);
}

// Round 11
// 85.069 us; speedup vs baseline: 1.0216x; 1.0216x over previous
//
#include <hip/hip_runtime.h>
#include <cstdint>
#include <cstddef>

#define BB 32
#define AA 8400
#define NBB 32
#define CC 80
#define TOPKN 10

// ===========================================================================
// K1: per (b,j) block (256t). Enumerate only anchors inside the gt box via
// the analytic 3-level grid (bit-exact recompute of (arange+0.5)*s in f32),
// exact d>1e-8 re-test. Per-thread top-10 insertion, then LDS merge tree
// with [256][11] u64 rows (stride 88B -> 2-way bank aliasing = free).
// key = align_bits<<32 | (8400-a): descending u64 == descending align,
// tie -> smaller anchor index (lax.top_k semantics).
// Side duties: zero posA/posI (t==0) and -1-fill assign_ws (grid-stride).
// ===========================================================================
__global__ __launch_bounds__(256) void gt_topk_kernel(
    const float* __restrict__ pred_scores, const float* __restrict__ pred_boxes,
    const int* __restrict__ gt_labels, const float* __restrict__ gt_boxes,
    const int* __restrict__ gt_mask,
    int* __restrict__ tk, int* __restrict__ posA, int* __restrict__ posI,
    int* __restrict__ assign_ws) {
  const int j = blockIdx.x, b = blockIdx.y, t = threadIdx.x;
  const int g = b * NBB + j;
  if (t == 0) { posA[g] = 0; posI[g] = 0; }

  // -1 fill of assign_ws (268800 ints = 67200 int4), spread over 1024 blocks
  {
    const int idx = g * 256 + t;
    if (idx < (BB * AA) / 4)
      reinterpret_cast<int4*>(assign_ws)[idx] = make_int4(-1, -1, -1, -1);
  }

  const float gx0 = gt_boxes[g * 4 + 0], gy0 = gt_boxes[g * 4 + 1];
  const float gx1 = gt_boxes[g * 4 + 2], gy1 = gt_boxes[g * 4 + 3];
  const int cls = gt_labels[g];
  const bool valid = (gt_mask[g] != 0);
  const float ga1 = (gx1 - gx0) * (gy1 - gy0);

  unsigned long long tkkey[TOPKN];
#pragma unroll
  for (int k = 0; k < TOPKN; k++) tkkey[k] = 0ull;

  if (valid) {
    const int strides[3] = {8, 16, 32};
    const int grids[3] = {80, 40, 20};
    const int offs[3] = {0, 6400, 8000};
    for (int lvl = 0; lvl < 3; lvl++) {
      const float s = (float)strides[lvl];
      const int n = grids[lvl], off = offs[lvl];
      int lx = max(0, (int)floorf(gx0 / s - 0.5f) - 1);
      int hx = min(n - 1, (int)ceilf(gx1 / s - 0.5f) + 1);
      int ly = max(0, (int)floorf(gy0 / s - 0.5f) - 1);
      int hy = min(n - 1, (int)ceilf(gy1 / s - 0.5f) + 1);
      if (hx < lx || hy < ly) continue;
      const int w = hx - lx + 1;
      const int m = w * (hy - ly + 1);
      for (int i = t; i < m; i += 256) {
        const int ix = lx + i % w;
        const int iy = ly + i / w;
        const float apx = ((float)ix + 0.5f) * s;
        const float apy = ((float)iy + 0.5f) * s;
        const float d = fminf(fminf(apx - gx0, apy - gy0),
                              fminf(gx1 - apx, gy1 - apy));
        if (!(d > 1e-8f)) continue;
        const int a = off + iy * n + ix;
        const float* pb = pred_boxes + ((size_t)b * AA + a) * 4;
        const float p0 = pb[0], p1 = pb[1], p2 = pb[2], p3 = pb[3];
        const float iw = fmaxf(fminf(gx1, p2) - fmaxf(gx0, p0), 0.0f);
        const float ih = fmaxf(fminf(gy1, p3) - fmaxf(gy0, p1), 0.0f);
        const float inter = iw * ih;
        const float a2 = (p2 - p0) * (p3 - p1);
        const float iou = fmaxf(inter / (ga1 + a2 - inter + 1e-10f), 0.0f);
        const float sc = pred_scores[((size_t)b * AA + a) * CC + cls];
        const float i2 = iou * iou;
        const float align_v = sc * i2 * i2 * i2;
        const unsigned long long key =
            ((unsigned long long)__float_as_uint(align_v) << 32) |
            (unsigned int)(AA - a);
        if (key > tkkey[TOPKN - 1]) {
          tkkey[TOPKN - 1] = key;
#pragma unroll
          for (int k = TOPKN - 1; k > 0; k--) {
            if (tkkey[k] > tkkey[k - 1]) {
              unsigned long long tmp = tkkey[k];
              tkkey[k] = tkkey[k - 1];
              tkkey[k - 1] = tmp;
            }
          }
        }
      }
    }
  }

  __shared__ unsigned long long s_key[256][TOPKN + 1];  // +1 pad: stride 88B
#pragma unroll
  for (int k = 0; k < TOPKN; k++) s_key[t][k] = tkkey[k];
  __syncthreads();

  for (int stride = 128; stride >= 1; stride >>= 1) {
    if (t < stride) {
      unsigned long long mk[TOPKN];
      int p = 0, q = 0;
#pragma unroll
      for (int k = 0; k < TOPKN; k++) {
        const unsigned long long k1 = s_key[t][p], k2 = s_key[t + stride][q];
        if (k1 >= k2) { mk[k] = k1; p++; } else { mk[k] = k2; q++; }
      }
#pragma unroll
      for (int k = 0; k < TOPKN; k++) s_key[t][k] = mk[k];
    }
    __syncthreads();
  }

  if (t < TOPKN) {
    const unsigned long long key = s_key[0][t];
    tk[g * TOPKN + t] = (key != 0ull) ? (AA - (int)(key & 0xffffffffu)) : -1;
  }
}

// ===========================================================================
// K2 (sparse): one block per batch b. Only the <=320 top-10 candidate
// anchors can be assigned. cnt(a) = #occurrences of a in the 320-entry LDS
// list (per-row lists are duplicate-free, so cnt == number of rows whose
// top-10 holds a). cnt==1 -> that row; cnt>1 -> first-max argmax_j of
// (valid & inside ? iou : 0) over all 32 gts (reference semantics).
// Duplicate entries of the same conflicted anchor write identical values.
// ===========================================================================
__global__ __launch_bounds__(256) void assign_sparse_kernel(
    const float* __restrict__ pred_scores, const float* __restrict__ pred_boxes,
    const float* __restrict__ anchor_points, const int* __restrict__ gt_labels,
    const float* __restrict__ gt_boxes, const int* __restrict__ gt_mask,
    const int* __restrict__ tk,
    int* __restrict__ assign_ws, float* __restrict__ align_ws,
    int* __restrict__ posA, int* __restrict__ posI) {
  const int b = blockIdx.x, t = threadIdx.x;

  __shared__ float sbox[NBB][4];
  __shared__ int scls[NBB];
  __shared__ int svalid[NBB];
  __shared__ int sa[NBB * TOPKN];  // 320 candidate anchor ids (-1 = empty)

  if (t < NBB) {
    const int g = b * NBB + t;
    sbox[t][0] = gt_boxes[g * 4 + 0];
    sbox[t][1] = gt_boxes[g * 4 + 1];
    sbox[t][2] = gt_boxes[g * 4 + 2];
    sbox[t][3] = gt_boxes[g * 4 + 3];
    scls[t] = gt_labels[g];
    svalid[t] = (gt_mask[g] != 0) ? 1 : 0;
  }
  for (int e = t; e < NBB * TOPKN; e += 256) sa[e] = tk[b * NBB * TOPKN + e];
  __syncthreads();

  for (int e = t; e < NBB * TOPKN; e += 256) {
    const int a = sa[e];
    if (a < 0) continue;
    const int j = e / TOPKN;

    int cnt = 0;
    for (int q = 0; q < NBB * TOPKN; q++) cnt += (sa[q] == a) ? 1 : 0;

    const float apx = anchor_points[a * 2 + 0];
    const float apy = anchor_points[a * 2 + 1];
    const float* pb = pred_boxes + ((size_t)b * AA + a) * 4;
    const float p0 = pb[0], p1 = pb[1], p2 = pb[2], p3 = pb[3];
    const float a2 = (p2 - p0) * (p3 - p1);

    int jj;
    float iou_f;
    if (cnt == 1) {
      jj = j;
      const float gx0 = sbox[j][0], gy0 = sbox[j][1];
      const float gx1 = sbox[j][2], gy1 = sbox[j][3];
      const float iw = fmaxf(fminf(gx1, p2) - fmaxf(gx0, p0), 0.0f);
      const float ih = fmaxf(fminf(gy1, p3) - fmaxf(gy0, p1), 0.0f);
      const float inter = iw * ih;
      const float a1 = (gx1 - gx0) * (gy1 - gy0);
      iou_f = fmaxf(inter / (a1 + a2 - inter + 1e-10f), 0.0f);
    } else {
      float best_iou = -1.0f;
      int best_j = 0;
      for (int jq = 0; jq < NBB; jq++) {
        const float gx0 = sbox[jq][0], gy0 = sbox[jq][1];
        const float gx1 = sbox[jq][2], gy1 = sbox[jq][3];
        const float d = fminf(fminf(apx - gx0, apy - gy0),
                              fminf(gx1 - apx, gy1 - apy));
        float iou = 0.0f;
        if (svalid[jq] && d > 1e-8f) {
          const float iw = fmaxf(fminf(gx1, p2) - fmaxf(gx0, p0), 0.0f);
          const float ih = fmaxf(fminf(gy1, p3) - fmaxf(gy0, p1), 0.0f);
          const float inter = iw * ih;
          const float a1 = (gx1 - gx0) * (gy1 - gy0);
          iou = fmaxf(inter / (a1 + a2 - inter + 1e-10f), 0.0f);
        }
        if (iou > best_iou) { best_iou = iou; best_j = jq; }  // first-max
      }
      jj = best_j;
      iou_f = best_iou;
    }

    const float sc = pred_scores[((size_t)b * AA + a) * CC + scls[jj]];
    const float i2 = iou_f * iou_f;
    const float align_v = sc * i2 * i2 * i2;
    assign_ws[b * AA + a] = jj;
    align_ws[b * AA + a] = align_v;
    atomicMax(&posA[b * NBB + jj], __float_as_int(align_v));
    atomicMax(&posI[b * NBB + jj], __float_as_int(iou_f));
  }
}

// ===========================================================================
// K3: write the whole output (unchanged, validated). One thread per float4
// chunk of the scores tensor (20/anchor); chunk-0 thread also writes
// label/box/fg.
// ===========================================================================
__global__ __launch_bounds__(256) void write_out_kernel(
    const int* __restrict__ gt_labels, const float* __restrict__ gt_boxes,
    const int* __restrict__ assign_in, const float* __restrict__ align_in,
    const int* __restrict__ posA, const int* __restrict__ posI,
    float* __restrict__ out) {
  const int idx = blockIdx.x * 256 + threadIdx.x;  // [0, BB*AA*20)
  const int aidx = idx / 20;
  const int c = idx - aidx * 20;
  const int b = aidx / AA;

  const int assign = assign_in[aidx];
  const int j0 = (assign >= 0) ? assign : 0;
  const int g = b * NBB + j0;
  int label = gt_labels[g];
  label = min(max(label, 0), 80);

  float* out_scores = out + (size_t)BB * AA * 5;
  float4 vv = make_float4(0.f, 0.f, 0.f, 0.f);
  if (assign >= 0 && c == (label >> 2)) {
    const float pa = __int_as_float(posA[b * NBB + assign]);
    const float pi = __int_as_float(posI[b * NBB + assign]);
    const float norm = align_in[aidx] * pi / (pa + 1e-8f);
    ((float*)&vv)[label & 3] = norm;
  }
  reinterpret_cast<float4*>(out_scores)[(size_t)aidx * 20 + c] = vv;

  if (c == 0) {
    out[aidx] = (float)label;
    float* out_boxes = out + (size_t)BB * AA;
    out_boxes[(size_t)aidx * 4 + 0] = gt_boxes[g * 4 + 0];
    out_boxes[(size_t)aidx * 4 + 1] = gt_boxes[g * 4 + 1];
    out_boxes[(size_t)aidx * 4 + 2] = gt_boxes[g * 4 + 2];
    out_boxes[(size_t)aidx * 4 + 3] = gt_boxes[g * 4 + 3];
    out[(size_t)BB * AA * 85 + aidx] = (assign >= 0) ? 1.0f : 0.0f;
  }
}

// ===========================================================================
extern "C" void kernel_launch(void* const* d_in, const int* in_sizes, int n_in,
                              void* d_out, int out_size, void* d_ws, size_t ws_size,
                              hipStream_t stream) {
  const float* pred_scores = (const float*)d_in[0];
  const float* pred_boxes = (const float*)d_in[1];
  const float* anchor_points = (const float*)d_in[2];
  const int* gt_labels = (const int*)d_in[3];
  const float* gt_boxes = (const float*)d_in[4];
  const int* gt_mask = (const int*)d_in[5];
  float* out = (float*)d_out;
  char* ws = (char*)d_ws;

  // workspace layout (bytes)
  const size_t sz_acc = (size_t)BB * AA * 4;               // 1.075 MB
  const size_t off_tk = 0;                                 // 1024*10*4 = 40KB
  const size_t off_posA = off_tk + (size_t)BB * NBB * TOPKN * 4;
  const size_t off_posI = off_posA + 4096;
  const size_t off_assign = off_posI + 4096;
  const size_t off_align = off_assign + sz_acc;

  int* tk = (int*)(ws + off_tk);
  int* posA = (int*)(ws + off_posA);
  int* posI = (int*)(ws + off_posI);
  int* assign_ws = (int*)(ws + off_assign);
  float* align_ws = (float*)(ws + off_align);

  dim3 g1(NBB, BB);
  gt_topk_kernel<<<g1, 256, 0, stream>>>(pred_scores, pred_boxes, gt_labels,
                                         gt_boxes, gt_mask, tk, posA, posI,
                                         assign_ws);

  assign_sparse_kernel<<<BB, 256, 0, stream>>>(
      pred_scores, pred_boxes, anchor_points, gt_labels, gt_boxes, gt_mask,
      tk, assign_ws, align_ws, posA, posI);

  const int nchunks = BB * AA * 20;
  write_out_kernel<<<(nchunks + 255) / 256, 256, 0, stream>>>(
      gt_labels, gt_boxes, assign_ws, align_ws, posA, posI, out);
}